// Round 16
// baseline (278.214 us; speedup 1.0000x reference)
//
#include <hip/hip_runtime.h>
#include <hip/hip_cooperative_groups.h>
#include <cstdint>
#include <cstddef>

namespace cg = cooperative_groups;

#define DEV __device__ __forceinline__

typedef __bf16 bf16x8 __attribute__((ext_vector_type(8)));
typedef float f32x4 __attribute__((ext_vector_type(4)));

#define NEG_VAL -10000.0f

DEV unsigned int f2bf(float f) {
    unsigned int u = __float_as_uint(f);
    return (u + 0x7FFFu + ((u >> 16) & 1u)) >> 16;   // RNE to bf16
}
DEV unsigned int pk2(float a, float b) { return f2bf(a) | (f2bf(b) << 16); }

DEV float sigf(float x)  { return __builtin_amdgcn_rcpf(1.f + __expf(-x)); }
DEV float tanhff(float x){ return 2.f * __builtin_amdgcn_rcpf(1.f + __expf(-2.f * x)) - 1.f; }

// ---------------------------------------------------------------------------
// Kernel 1: cast ALL weights fp32 -> bf16, 16x16x32 register-direct tiles:
// tile = 8192 u16; element (col,k) at uint4 idx (col>>4)*64 + (k>>3)*16 + (col&15).
// ---------------------------------------------------------------------------
__global__ void cast_all_kernel(const float* __restrict__ cw3,
                                const float* __restrict__ cw4,
                                const float* __restrict__ cw5,
                                const float* __restrict__ Wih0f,
                                const float* __restrict__ Wih0b,
                                const float* __restrict__ Wih1f,
                                const float* __restrict__ Wih1b,
                                unsigned short* __restrict__ wbc,
                                unsigned short* __restrict__ wih0c,
                                unsigned short* __restrict__ wih1c) {
    int tid = blockIdx.x * blockDim.x + threadIdx.x;
    const float* src;
    uint4* dstp;
    if (tid < 294912) {                       // conv: 12*24*256*4
        int g   = tid & 3;
        int col = (tid >> 2) & 255;
        int c   = (tid >> 10) % 24;
        int p   = tid / (24 * 256 * 4);
        int sz, j; const float* W;
        if (p < 3)      { sz = 3; j = p;     W = cw3; }
        else if (p < 7) { sz = 4; j = p - 3; W = cw4; }
        else            { sz = 5; j = p - 7; W = cw5; }
        src = W + ((size_t)col * sz + j) * 768 + c * 32 + g * 8;
        dstp = reinterpret_cast<uint4*>(wbc) +
               ((size_t)(p * 24 + c) * 1024 + (col >> 4) * 64 + g * 16 + (col & 15));
    } else if (tid < 294912 + 49152) {        // Wih0: 2*24*256*4
        int u   = tid - 294912;
        int g   = u & 3;
        int col = (u >> 2) & 255;
        int kc  = (u >> 10) % 24;
        int dir = u / (24 * 256 * 4);
        const float* W = dir ? Wih0b : Wih0f;
        src = W + (size_t)col * 768 + kc * 32 + g * 8;
        dstp = reinterpret_cast<uint4*>(wih0c) +
               ((size_t)(dir * 24 + kc) * 1024 + (col >> 4) * 64 + g * 16 + (col & 15));
    } else if (tid < 294912 + 49152 + 8192) { // Wih1: 2*4*256*4
        int u   = tid - 294912 - 49152;
        int g   = u & 3;
        int col = (u >> 2) & 255;
        int kc  = (u >> 10) % 4;
        int dir = u / (4 * 256 * 4);
        const float* W = dir ? Wih1b : Wih1f;
        src = W + (size_t)col * 128 + kc * 32 + g * 8;
        dstp = reinterpret_cast<uint4*>(wih1c) +
               ((size_t)(dir * 4 + kc) * 1024 + (col >> 4) * 64 + g * 16 + (col & 15));
    } else return;
    float4 a = *(const float4*)(src);
    float4 b = *(const float4*)(src + 4);
    *dstp = make_uint4(pk2(a.x, a.y), pk2(a.z, a.w), pk2(b.x, b.y), pk2(b.z, b.w));
}

// ---------------------------------------------------------------------------
// Kernel 2: conv via MFMA (R8/R15 structure, best-measured ~138us).
// ---------------------------------------------------------------------------
template<int SZ>
DEV void conv_body(const int* __restrict__ ids,
                   const float* __restrict__ emb,
                   const unsigned short* __restrict__ wbc,
                   const float* __restrict__ cb,
                   unsigned short* __restrict__ para_bf,
                   int pair, int szi, int pbase,
                   unsigned short* Xlds)
{
    int tid  = threadIdx.x;
    int lane = tid & 63;
    int nw   = tid >> 6;
    int l15  = lane & 15;
    int q    = lane >> 4;
    int n0   = pair * 2;

    int srow  = tid >> 1;
    int shalf = tid & 1;
    int sid   = ids[(n0 + (srow >> 6)) * 64 + (srow & 63)];
    const float* embrow = emb + (size_t)sid * 768 + shalf * 16;
    int skey = (srow >> 1) & 3;
    int xo0 = srow * 32 + (((2 * shalf)     ^ skey) * 8);
    int xo1 = srow * 32 + (((2 * shalf + 1) ^ skey) * 8);

    int vlaneB = nw * 2048 + lane * 8;

    f32x4 acc[8][4];
    #pragma unroll
    for (int a = 0; a < 8; a++)
        #pragma unroll
        for (int t = 0; t < 4; t++) acc[a][t] = (f32x4){0.f, 0.f, 0.f, 0.f};

    bf16x8 bfr[2][4];
    float4 e0, e1, e2, e3;

    {
        e0 = ((const float4*)embrow)[0];
        e1 = ((const float4*)embrow)[1];
        e2 = ((const float4*)embrow)[2];
        e3 = ((const float4*)embrow)[3];
        const unsigned short* bt = wbc + (size_t)(pbase * 24) * 8192 + vlaneB;
        #pragma unroll
        for (int t = 0; t < 4; t++)
            bfr[0][t] = *(const bf16x8*)(bt + t * 512);
        uint4 p0 = make_uint4(pk2(e0.x, e0.y), pk2(e0.z, e0.w),
                              pk2(e1.x, e1.y), pk2(e1.z, e1.w));
        uint4 p1 = make_uint4(pk2(e2.x, e2.y), pk2(e2.z, e2.w),
                              pk2(e3.x, e3.y), pk2(e3.z, e3.w));
        *(uint4*)&Xlds[xo0] = p0;
        *(uint4*)&Xlds[xo1] = p1;
        asm volatile("s_waitcnt lgkmcnt(0)" ::: "memory");
        __builtin_amdgcn_s_barrier();
    }

    int cbase = pbase * 24;
    for (int c2 = 0; c2 < 24; c2 += 2, cbase += 2) {
        #pragma unroll
        for (int s2 = 0; s2 < 2 * SZ; ++s2) {
            const int half = (s2 < SZ) ? 0 : 1;
            const int j    = s2 - half * SZ;
            const int par  = s2 & 1;
            {
                const int sP = s2 + 1;
                const int offP = (sP < SZ) ? sP * 24
                               : (sP < 2 * SZ ? (sP - SZ) * 24 + 1 : 2);
                const unsigned short* bt =
                    wbc + (size_t)(cbase + offP) * 8192 + vlaneB;
                #pragma unroll
                for (int t = 0; t < 4; t++)
                    bfr[par ^ 1][t] = *(const bf16x8*)(bt + t * 512);
            }
            if (s2 == 0 || s2 == SZ) {
                int cE = half ? c2 + 2 : c2 + 1; if (cE > 23) cE = 0;
                const float* sp = embrow + cE * 32;
                e0 = ((const float4*)sp)[0];
                e1 = ((const float4*)sp)[1];
                e2 = ((const float4*)sp)[2];
                e3 = ((const float4*)sp)[3];
            }

            const unsigned short* Xb = Xlds + half * 4096;
            {
                bf16x8 af[4];
                #pragma unroll
                for (int a = 0; a < 4; a++) {
                    int pp = 16 * a + l15 + j; if (pp > 63) pp = 63;
                    af[a] = *(const bf16x8*)(
                        &Xb[pp * 32 + ((q ^ ((pp >> 1) & 3)) * 8)]);
                }
                __builtin_amdgcn_s_setprio(1);
                #pragma unroll
                for (int a = 0; a < 4; a++)
                    #pragma unroll
                    for (int t = 0; t < 4; t++)
                        acc[a][t] = __builtin_amdgcn_mfma_f32_16x16x32_bf16(
                            af[a], bfr[par][t], acc[a][t], 0, 0, 0);
                __builtin_amdgcn_s_setprio(0);
            }
            {
                bf16x8 af[4];
                #pragma unroll
                for (int a = 0; a < 4; a++) {
                    int pp = 16 * a + l15 + j; if (pp > 63) pp = 63;
                    int xr = 64 + pp;
                    af[a] = *(const bf16x8*)(
                        &Xb[xr * 32 + ((q ^ ((xr >> 1) & 3)) * 8)]);
                }
                __builtin_amdgcn_s_setprio(1);
                #pragma unroll
                for (int a = 0; a < 4; a++)
                    #pragma unroll
                    for (int t = 0; t < 4; t++)
                        acc[4 + a][t] = __builtin_amdgcn_mfma_f32_16x16x32_bf16(
                            af[a], bfr[par][t], acc[4 + a][t], 0, 0, 0);
                __builtin_amdgcn_s_setprio(0);
            }

            if (j == SZ - 1) {
                unsigned short* Xw = Xlds + (half ^ 1) * 4096;
                uint4 p0 = make_uint4(pk2(e0.x, e0.y), pk2(e0.z, e0.w),
                                      pk2(e1.x, e1.y), pk2(e1.z, e1.w));
                uint4 p1 = make_uint4(pk2(e2.x, e2.y), pk2(e2.z, e2.w),
                                      pk2(e3.x, e3.y), pk2(e3.z, e3.w));
                *(uint4*)&Xw[xo0] = p0;
                *(uint4*)&Xw[xo1] = p1;
                asm volatile("s_waitcnt lgkmcnt(0)" ::: "memory");
                __builtin_amdgcn_s_barrier();
            }
        }
    }

    int pmax = 64 - SZ;
    #pragma unroll
    for (int t = 0; t < 4; t++) {
        int colb = nw * 64 + t * 16;
        float bias = cb[colb + l15];
        #pragma unroll
        for (int s = 0; s < 2; s++) {
            float m = 0.0f;
            #pragma unroll
            for (int a4 = 0; a4 < 4; a4++) {
                #pragma unroll
                for (int r = 0; r < 4; r++) {
                    int p = 16 * a4 + q * 4 + r;
                    float v = acc[s * 4 + a4][t][r] + bias;
                    v = v > 0.f ? v : 0.f;
                    if (p <= pmax) m = v > m ? v : m;
                }
            }
            m = fmaxf(m, __shfl_xor(m, 16));
            m = fmaxf(m, __shfl_xor(m, 32));
            if (lane < 16) {
                int n = n0 + s;
                int row = (n & 63) * 8 + (n >> 6);     // t*8 + b
                para_bf[(size_t)row * 768 + szi * 256 + colb + lane] =
                    (unsigned short)f2bf(m);
            }
        }
    }
}

__global__ __launch_bounds__(256, 2) void conv_pool_kernel(
    const int* __restrict__ ids,
    const float* __restrict__ emb,
    const unsigned short* __restrict__ wbc,
    const float* __restrict__ cb3, const float* __restrict__ cb4,
    const float* __restrict__ cb5,
    unsigned short* __restrict__ para_bf)
{
    __shared__ unsigned short Xlds[2][4096];
    int bx   = blockIdx.x;
    int szi  = 2 - (bx >> 8);      // DESCENDING: conv5 blocks dispatch first
    int pair = bx & 255;
    if (szi == 0)
        conv_body<3>(ids, emb, wbc, cb3, para_bf, pair, 0, 0, &Xlds[0][0]);
    else if (szi == 1)
        conv_body<4>(ids, emb, wbc, cb4, para_bf, pair, 1, 3, &Xlds[0][0]);
    else
        conv_body<5>(ids, emb, wbc, cb5, para_bf, pair, 2, 7, &Xlds[0][0]);
}

// ---------------------------------------------------------------------------
// Fused tail (cooperative, 32 blocks x 256 thr):
//   A: gemm layer0   B: lstm layer0   C: gemm layer1   D: lstm layer1   E: crf
// Phase bodies identical to R15 kernels; grid.sync() between phases.
// ---------------------------------------------------------------------------
struct TailArgs {
    const unsigned short* para_bf;
    const unsigned short* wih0c;
    const unsigned short* wih1c;
    const float *bih0f, *bhh0f, *bih0b, *bhh0b;
    const float *bih1f, *bhh1f, *bih1b, *bhh1b;
    const float *Whh0f, *Whh0b, *Whh1f, *Whh1b;
    float* gates;            // (2,64,256,8) + pad
    unsigned short* h0_bf;   // (64,8,128) bf16 (aliases para_bf region)
    float* h1f;              // (64,8,128)
    const float* lin_w; const float* lin_b;
    const float* mask; const int* tags; const float* trans;
    float* out;
};

template<int KC>
DEV void gemm_phase(int bx,
                    const unsigned short* __restrict__ xbf,
                    const unsigned short* __restrict__ wihc,
                    const float* bihF, const float* bhhF,
                    const float* bihB, const float* bhhB,
                    float* __restrict__ gates2)
{
    const int din = KC * 32;
    int dir  = bx >> 4;
    int rowg = (bx >> 1) & 7;
    int colg = bx & 1;
    int tid  = threadIdx.x;
    int lane = tid & 63;
    int wid  = tid >> 6;
    int mw   = wid >> 1;
    int nw   = wid & 1;
    int l15  = lane & 15;
    int q    = lane >> 4;

    const float* bih = dir ? bihB : bihF;
    const float* bhh = dir ? bhhB : bhhF;
    const unsigned short* wt = wihc + (size_t)dir * KC * 8192;

    const unsigned short* arow[2];
    #pragma unroll
    for (int a = 0; a < 2; a++)
        arow[a] = xbf + (size_t)(rowg * 64 + mw * 32 + a * 16 + l15) * din + q * 8;
    const unsigned short* bbase = wt + (colg * 8 + nw * 4) * 512 + lane * 8;

    f32x4 acc[2][4];
    #pragma unroll
    for (int a = 0; a < 2; a++)
        #pragma unroll
        for (int t = 0; t < 4; t++) acc[a][t] = (f32x4){0.f, 0.f, 0.f, 0.f};

    bf16x8 afb[4][2], bfb[4][4];
    #pragma unroll
    for (int s = 0; s < 3; s++) {
        int k0 = (s < KC) ? s : KC - 1;
        #pragma unroll
        for (int a = 0; a < 2; a++)
            afb[s][a] = *(const bf16x8*)(arow[a] + k0 * 32);
        #pragma unroll
        for (int t = 0; t < 4; t++)
            bfb[s][t] = *(const bf16x8*)(bbase + (size_t)k0 * 8192 + t * 512);
    }

    #pragma unroll 4
    for (int kc = 0; kc < KC; ++kc) {
        const int p  = kc & 3;
        const int pn = (kc + 3) & 3;
        int kn = (kc + 3 < KC) ? kc + 3 : KC - 1;
        #pragma unroll
        for (int a = 0; a < 2; a++)
            afb[pn][a] = *(const bf16x8*)(arow[a] + kn * 32);
        #pragma unroll
        for (int t = 0; t < 4; t++)
            bfb[pn][t] = *(const bf16x8*)(bbase + (size_t)kn * 8192 + t * 512);
        #pragma unroll
        for (int a = 0; a < 2; a++)
            #pragma unroll
            for (int t = 0; t < 4; t++)
                acc[a][t] = __builtin_amdgcn_mfma_f32_16x16x32_bf16(
                    afb[p][a], bfb[p][t], acc[a][t], 0, 0, 0);
    }

    #pragma unroll
    for (int tt = 0; tt < 4; tt++) {
        int nn = colg * 128 + nw * 64 + tt * 16 + l15;
        float bb = bih[nn] + bhh[nn];
        #pragma unroll
        for (int a = 0; a < 2; a++) {
            int m = rowg * 64 + mw * 32 + q * 4 + a * 16;   // t*8+b
            int tcol = m >> 3, b0 = m & 7;
            f32x4 v = acc[a][tt];
            v[0] += bb; v[1] += bb; v[2] += bb; v[3] += bb;
            *(f32x4*)(gates2 + (((size_t)dir * 64 + tcol) * 256 + nn) * 8 + b0) = v;
        }
    }
}

DEV void lstm_phase(char* smemraw, int dir,
                    const float* __restrict__ gates2,
                    const float* __restrict__ Whh,
                    float* __restrict__ houtF,
                    unsigned short* __restrict__ houtB)
{
    unsigned short (*h16)[16 * 64] =
        reinterpret_cast<unsigned short (*)[16 * 64]>(smemraw);
    const float* gin = gates2 + (size_t)dir * 64 * 256 * 8;

    int tid  = threadIdx.x;
    int lane = tid & 63;
    int w    = tid >> 6;
    int l15  = lane & 15;
    int q    = lane >> 4;
    int hh   = 16 * w + l15;

    bf16x8 Bf[4][2];
    #pragma unroll
    for (int g = 0; g < 4; g++)
        #pragma unroll
        for (int kh = 0; kh < 2; kh++) {
            const float* wp = Whh + (size_t)(g * 64 + hh) * 64 + kh * 32 + q * 8;
            float4 f0 = *(const float4*)wp;
            float4 f1 = *(const float4*)(wp + 4);
            bf16x8 r;
            r[0] = (__bf16)f0.x; r[1] = (__bf16)f0.y;
            r[2] = (__bf16)f0.z; r[3] = (__bf16)f0.w;
            r[4] = (__bf16)f1.x; r[5] = (__bf16)f1.y;
            r[6] = (__bf16)f1.z; r[7] = (__bf16)f1.w;
            Bf[g][kh] = r;
        }

    const float* pgB[4];
    #pragma unroll
    for (int g = 0; g < 4; g++)
        pgB[g] = gin + (size_t)(g * 64 + hh) * 8 + 4 * q;

    for (int i = tid; i < 2 * 16 * 64; i += 256)
        ((unsigned short*)h16)[i] = 0;
    float cst[4] = {0.f, 0.f, 0.f, 0.f};
    __syncthreads();

    f32x4 gvp[4][4];
    #pragma unroll
    for (int d = 0; d < 3; d++) {
        int td = dir ? 63 - d : d;
        #pragma unroll
        for (int g = 0; g < 4; g++)
            gvp[d][g] = *(const f32x4*)(pgB[g] + (size_t)td * 2048);
    }

    #pragma unroll 4
    for (int s = 0; s < 64; ++s) {
        const int slot = s & 3;
        int t = dir ? 63 - s : s;
        const unsigned short* hb = h16[s & 1];
        int slot0 = q ^ (l15 & 7);
        int slot1 = (4 + q) ^ (l15 & 7);
        bf16x8 a0 = *(const bf16x8*)&hb[l15 * 64 + slot0 * 8];
        bf16x8 a1 = *(const bf16x8*)&hb[l15 * 64 + slot1 * 8];

        f32x4 acc[4];
        #pragma unroll
        for (int g = 0; g < 4; g++) {
            acc[g] = __builtin_amdgcn_mfma_f32_16x16x32_bf16(a0, Bf[g][0], gvp[slot][g], 0, 0, 0);
            acc[g] = __builtin_amdgcn_mfma_f32_16x16x32_bf16(a1, Bf[g][1], acc[g], 0, 0, 0);
        }

        {
            int sn = (s + 3 < 64) ? s + 3 : 63;
            int tn = dir ? 63 - sn : sn;
            const int slotn = (s + 3) & 3;
            #pragma unroll
            for (int g = 0; g < 4; g++)
                gvp[slotn][g] = *(const f32x4*)(pgB[g] + (size_t)tn * 2048);
        }

        if (q < 2) {
            unsigned short* hw = h16[(s + 1) & 1];
            #pragma unroll
            for (int r = 0; r < 4; r++) {
                int b = 4 * q + r;
                float gi = acc[0][r];
                float gf = acc[1][r];
                float gg = acc[2][r];
                float go = acc[3][r];
                float cn = sigf(gf) * cst[r] + sigf(gi) * tanhff(gg);
                float hv = sigf(go) * tanhff(cn);
                cst[r] = cn;
                int slotw = (hh >> 3) ^ (b & 7);
                hw[b * 64 + slotw * 8 + (hh & 7)] = (unsigned short)f2bf(hv);
                size_t oi = ((size_t)t * 8 + b) * 128 + dir * 64 + hh;
                if (houtF) houtF[oi] = hv;
                houtB[oi] = (unsigned short)f2bf(hv);
            }
        }
        __syncthreads();
    }
}

struct CrfSmem {
    float feats[64][8][5];
    float wl[5][128];
    float msk[512];
    int   tgs[512];
    float fwd_s[8], gold_s[8];
    float tr[25], trE[5], lb[5];
};

DEV void crf_phase(char* smemraw,
                   const float* __restrict__ h1,
                   const float* __restrict__ lin_w,
                   const float* __restrict__ lin_b,
                   const float* __restrict__ mask,
                   const int* __restrict__ tags,
                   const float* __restrict__ trans,
                   float* __restrict__ out)
{
    CrfSmem& S = *reinterpret_cast<CrfSmem*>(smemraw);
    int tid = threadIdx.x;
    if (tid < 25) S.tr[tid] = trans[tid];
    if (tid < 5) { S.trE[tid] = trans[20 + tid]; S.lb[tid] = lin_b[tid]; }
    for (int i = tid; i < 512; i += 256) {
        S.msk[i] = mask[i];
        S.tgs[i] = tags[i];
    }
    if (tid < 128) {
        #pragma unroll
        for (int i = 0; i < 5; i++) S.wl[i][tid] = lin_w[i * 128 + tid];
    }
    __syncthreads();

    for (int rr = tid; rr < 512; rr += 256) {
        const float4* h4 = (const float4*)(h1 + (size_t)rr * 128);
        float a0 = 0.f, a1 = 0.f, a2 = 0.f, a3 = 0.f, a4 = 0.f;
        for (int e4 = 0; e4 < 32; e4++) {
            float4 hv = h4[e4];
            int e = e4 * 4;
            a0 += hv.x * S.wl[0][e] + hv.y * S.wl[0][e+1] + hv.z * S.wl[0][e+2] + hv.w * S.wl[0][e+3];
            a1 += hv.x * S.wl[1][e] + hv.y * S.wl[1][e+1] + hv.z * S.wl[1][e+2] + hv.w * S.wl[1][e+3];
            a2 += hv.x * S.wl[2][e] + hv.y * S.wl[2][e+1] + hv.z * S.wl[2][e+2] + hv.w * S.wl[2][e+3];
            a3 += hv.x * S.wl[3][e] + hv.y * S.wl[3][e+1] + hv.z * S.wl[3][e+2] + hv.w * S.wl[3][e+3];
            a4 += hv.x * S.wl[4][e] + hv.y * S.wl[4][e+1] + hv.z * S.wl[4][e+2] + hv.w * S.wl[4][e+3];
        }
        float m = S.msk[rr];
        int t = rr >> 3, b = rr & 7;
        S.feats[t][b][0] = (m * a0 + S.lb[0]) * m;
        S.feats[t][b][1] = (m * a1 + S.lb[1]) * m;
        S.feats[t][b][2] = (m * a2 + S.lb[2]) * m;
        S.feats[t][b][3] = (m * a3 + S.lb[3]) * m;
        S.feats[t][b][4] = (m * a4 + S.lb[4]) * m;
    }
    __syncthreads();

    if (tid < 40) {    // wave 0, lane = b*5+i
        int b = tid / 5, i = tid % 5;
        float alpha = (i == 0) ? 0.f : NEG_VAL;
        float trow[5];
        #pragma unroll
        for (int j2 = 0; j2 < 5; j2++) trow[j2] = S.tr[i * 5 + j2];
        for (int t = 0; t < 64; t++) {
            float s0, s1, s2, s3, s4;
            s0 = __shfl(alpha, b * 5 + 0, 64) + trow[0];
            s1 = __shfl(alpha, b * 5 + 1, 64) + trow[1];
            s2 = __shfl(alpha, b * 5 + 2, 64) + trow[2];
            s3 = __shfl(alpha, b * 5 + 3, 64) + trow[3];
            s4 = __shfl(alpha, b * 5 + 4, 64) + trow[4];
            float mx = fmaxf(fmaxf(fmaxf(s0, s1), fmaxf(s2, s3)), s4);
            float sum = expf(s0 - mx) + expf(s1 - mx) + expf(s2 - mx) +
                        expf(s3 - mx) + expf(s4 - mx);
            float lse = mx + logf(sum) + S.feats[t][b][i];
            float mt = S.msk[t * 8 + b];
            alpha = mt * lse + (1.f - mt) * alpha;
        }
        float v = alpha + S.trE[i];
        float m0 = __shfl(v, b * 5 + 0, 64);
        float m1 = __shfl(v, b * 5 + 1, 64);
        float m2 = __shfl(v, b * 5 + 2, 64);
        float m3 = __shfl(v, b * 5 + 3, 64);
        float m4 = __shfl(v, b * 5 + 4, 64);
        float mx = fmaxf(fmaxf(fmaxf(m0, m1), fmaxf(m2, m3)), m4);
        float sum = expf(m0 - mx) + expf(m1 - mx) + expf(m2 - mx) +
                    expf(m3 - mx) + expf(m4 - mx);
        if (i == 0) S.fwd_s[b] = mx + logf(sum);
    }
    if (tid >= 64 && tid < 72) {
        int b = tid - 64;
        float g = 0.f, lenf = 0.f;
        int prev = 0;   // SOS
        for (int t = 0; t < 64; t++) {
            int tg = S.tgs[t * 8 + b];
            float mt = S.msk[t * 8 + b];
            g += (S.feats[t][b][tg] + S.tr[tg * 5 + prev]) * mt;
            lenf += mt;
            prev = tg;
        }
        int len = (int)lenf;
        int last = (len == 0) ? 0 : S.tgs[(len - 1) * 8 + b];
        g += S.trE[last];
        S.gold_s[b] = g;
    }
    __syncthreads();
    if (tid == 0) {
        float s = 0.f;
        for (int b = 0; b < 8; b++) s += S.fwd_s[b] - S.gold_s[b];
        out[0] = s;
    }
}

__global__ __launch_bounds__(256) void tail_kernel(TailArgs a)
{
    cg::grid_group grid = cg::this_grid();
    __shared__ __align__(16) char smem[sizeof(CrfSmem)];
    int bx = blockIdx.x;

    // A: gemm layer0
    gemm_phase<24>(bx, a.para_bf, a.wih0c, a.bih0f, a.bhh0f, a.bih0b, a.bhh0b,
                   a.gates);
    grid.sync();
    // B: lstm layer0 (h0 bf16 overwrites para_bf region -- ordered by sync)
    if (bx < 2)
        lstm_phase(smem, bx, a.gates, bx ? a.Whh0b : a.Whh0f,
                   (float*)nullptr, a.h0_bf);
    grid.sync();
    // C: gemm layer1
    gemm_phase<4>(bx, a.h0_bf, a.wih1c, a.bih1f, a.bhh1f, a.bih1b, a.bhh1b,
                  a.gates);
    grid.sync();
    // D: lstm layer1 (bf16 h goes to scratch = h0_bf, fp32 h to h1f)
    if (bx < 2)
        lstm_phase(smem, bx, a.gates, bx ? a.Whh1b : a.Whh1f,
                   a.h1f, a.h0_bf);
    grid.sync();
    // E: crf
    if (bx == 0)
        crf_phase(smem, a.h1f, a.lin_w, a.lin_b, a.mask, a.tags, a.trans,
                  a.out);
}

// ---------------------------------------------------------------------------
extern "C" void kernel_launch(void* const* d_in, const int* in_sizes, int n_in,
                              void* d_out, int out_size, void* d_ws, size_t ws_size,
                              hipStream_t stream) {
    const int*   ids   = (const int*)d_in[0];
    const int*   tags  = (const int*)d_in[1];
    const float* mask  = (const float*)d_in[2];
    const float* emb   = (const float*)d_in[4];
    const float* cw3   = (const float*)d_in[5];
    const float* cb3   = (const float*)d_in[6];
    const float* cw4   = (const float*)d_in[7];
    const float* cb4   = (const float*)d_in[8];
    const float* cw5   = (const float*)d_in[9];
    const float* cb5   = (const float*)d_in[10];
    const float* Wih0f = (const float*)d_in[11];
    const float* Whh0f = (const float*)d_in[12];
    const float* bih0f = (const float*)d_in[13];
    const float* bhh0f = (const float*)d_in[14];
    const float* Wih0b = (const float*)d_in[15];
    const float* Whh0b = (const float*)d_in[16];
    const float* bih0b = (const float*)d_in[17];
    const float* bhh0b = (const float*)d_in[18];
    const float* Wih1f = (const float*)d_in[19];
    const float* Whh1f = (const float*)d_in[20];
    const float* bih1f = (const float*)d_in[21];
    const float* bhh1f = (const float*)d_in[22];
    const float* Wih1b = (const float*)d_in[23];
    const float* Whh1b = (const float*)d_in[24];
    const float* bih1b = (const float*)d_in[25];
    const float* bhh1b = (const float*)d_in[26];
    const float* lin_w = (const float*)d_in[27];
    const float* lin_b = (const float*)d_in[28];
    const float* trans = (const float*)d_in[29];

    char* ws = (char*)d_ws;
    unsigned short* wbc     = (unsigned short*)ws;
    unsigned short* wih0c   = (unsigned short*)(ws + 4718592);
    unsigned short* wih1c   = (unsigned short*)(ws + 5505024);
    unsigned short* para_bf = (unsigned short*)(ws + 5636096);
    float*          gates   = (float*)(ws + 6422528);   // 1MB + pad tail
    unsigned short* h0_bf   = (unsigned short*)(ws + 5636096);
    float*          h1f     = (float*)(ws + 4718592);

    hipLaunchKernelGGL(cast_all_kernel, dim3(1376), dim3(256), 0, stream,
                       cw3, cw4, cw5, Wih0f, Wih0b, Wih1f, Wih1b,
                       wbc, wih0c, wih1c);
    hipLaunchKernelGGL(conv_pool_kernel, dim3(768), dim3(256), 0, stream,
                       ids, emb, wbc, cb3, cb4, cb5, para_bf);

    TailArgs ta;
    ta.para_bf = para_bf;
    ta.wih0c = wih0c; ta.wih1c = wih1c;
    ta.bih0f = bih0f; ta.bhh0f = bhh0f; ta.bih0b = bih0b; ta.bhh0b = bhh0b;
    ta.bih1f = bih1f; ta.bhh1f = bhh1f; ta.bih1b = bih1b; ta.bhh1b = bhh1b;
    ta.Whh0f = Whh0f; ta.Whh0b = Whh0b; ta.Whh1f = Whh1f; ta.Whh1b = Whh1b;
    ta.gates = gates; ta.h0_bf = h0_bf; ta.h1f = h1f;
    ta.lin_w = lin_w; ta.lin_b = lin_b;
    ta.mask = mask; ta.tags = tags; ta.trans = trans;
    ta.out = (float*)d_out;
    void* args[] = { &ta };
    hipLaunchCooperativeKernel(reinterpret_cast<void*>(tail_kernel),
                               dim3(32), dim3(256), args, 0, stream);
}

// Round 17
// 250.277 us; speedup vs baseline: 1.1116x; 1.1116x over previous
//
#include <hip/hip_runtime.h>
#include <cstdint>
#include <cstddef>

#define DEV __device__ __forceinline__

typedef __bf16 bf16x8 __attribute__((ext_vector_type(8)));
typedef float f32x4 __attribute__((ext_vector_type(4)));

#define NEG_VAL -10000.0f

DEV unsigned int f2bf(float f) {
    unsigned int u = __float_as_uint(f);
    return (u + 0x7FFFu + ((u >> 16) & 1u)) >> 16;   // RNE to bf16
}
DEV unsigned int pk2(float a, float b) { return f2bf(a) | (f2bf(b) << 16); }

DEV float sigf(float x)  { return __builtin_amdgcn_rcpf(1.f + __expf(-x)); }
DEV float tanhff(float x){ return 2.f * __builtin_amdgcn_rcpf(1.f + __expf(-2.f * x)) - 1.f; }

// ---------------------------------------------------------------------------
// Kernel 1: cast ALL weights fp32 -> bf16, 16x16x32 register-direct tiles:
// tile = 8192 u16; element (col,k) at uint4 idx (col>>4)*64 + (k>>3)*16 + (col&15).
// ---------------------------------------------------------------------------
__global__ void cast_all_kernel(const float* __restrict__ cw3,
                                const float* __restrict__ cw4,
                                const float* __restrict__ cw5,
                                const float* __restrict__ Wih0f,
                                const float* __restrict__ Wih0b,
                                const float* __restrict__ Wih1f,
                                const float* __restrict__ Wih1b,
                                unsigned short* __restrict__ wbc,
                                unsigned short* __restrict__ wih0c,
                                unsigned short* __restrict__ wih1c) {
    int tid = blockIdx.x * blockDim.x + threadIdx.x;
    const float* src;
    uint4* dstp;
    if (tid < 294912) {                       // conv: 12*24*256*4
        int g   = tid & 3;
        int col = (tid >> 2) & 255;
        int c   = (tid >> 10) % 24;
        int p   = tid / (24 * 256 * 4);
        int sz, j; const float* W;
        if (p < 3)      { sz = 3; j = p;     W = cw3; }
        else if (p < 7) { sz = 4; j = p - 3; W = cw4; }
        else            { sz = 5; j = p - 7; W = cw5; }
        src = W + ((size_t)col * sz + j) * 768 + c * 32 + g * 8;
        dstp = reinterpret_cast<uint4*>(wbc) +
               ((size_t)(p * 24 + c) * 1024 + (col >> 4) * 64 + g * 16 + (col & 15));
    } else if (tid < 294912 + 49152) {        // Wih0: 2*24*256*4
        int u   = tid - 294912;
        int g   = u & 3;
        int col = (u >> 2) & 255;
        int kc  = (u >> 10) % 24;
        int dir = u / (24 * 256 * 4);
        const float* W = dir ? Wih0b : Wih0f;
        src = W + (size_t)col * 768 + kc * 32 + g * 8;
        dstp = reinterpret_cast<uint4*>(wih0c) +
               ((size_t)(dir * 24 + kc) * 1024 + (col >> 4) * 64 + g * 16 + (col & 15));
    } else if (tid < 294912 + 49152 + 8192) { // Wih1: 2*4*256*4
        int u   = tid - 294912 - 49152;
        int g   = u & 3;
        int col = (u >> 2) & 255;
        int kc  = (u >> 10) % 4;
        int dir = u / (4 * 256 * 4);
        const float* W = dir ? Wih1b : Wih1f;
        src = W + (size_t)col * 128 + kc * 32 + g * 8;
        dstp = reinterpret_cast<uint4*>(wih1c) +
               ((size_t)(dir * 4 + kc) * 1024 + (col >> 4) * 64 + g * 16 + (col & 15));
    } else return;
    float4 a = *(const float4*)(src);
    float4 b = *(const float4*)(src + 4);
    *dstp = make_uint4(pk2(a.x, a.y), pk2(a.z, a.w), pk2(b.x, b.y), pk2(b.z, b.w));
}

// ---------------------------------------------------------------------------
// Kernel 2: conv via MFMA (R8 structure): disjoint B quarters, acc[8][4],
// szi-descending grid order. Best-measured configuration (conv ~138us).
// ---------------------------------------------------------------------------
template<int SZ>
DEV void conv_body(const int* __restrict__ ids,
                   const float* __restrict__ emb,
                   const unsigned short* __restrict__ wbc,
                   const float* __restrict__ cb,
                   unsigned short* __restrict__ para_bf,
                   int pair, int szi, int pbase,
                   unsigned short* Xlds)
{
    int tid  = threadIdx.x;
    int lane = tid & 63;
    int nw   = tid >> 6;        // 0..3: 64-col quarter
    int l15  = lane & 15;
    int q    = lane >> 4;
    int n0   = pair * 2;

    int srow  = tid >> 1;       // 0..127
    int shalf = tid & 1;
    int sid   = ids[(n0 + (srow >> 6)) * 64 + (srow & 63)];
    const float* embrow = emb + (size_t)sid * 768 + shalf * 16;
    int skey = (srow >> 1) & 3;
    int xo0 = srow * 32 + (((2 * shalf)     ^ skey) * 8);
    int xo1 = srow * 32 + (((2 * shalf + 1) ^ skey) * 8);

    int vlaneB = nw * 2048 + lane * 8;     // u16 units, quarter base

    f32x4 acc[8][4];
    #pragma unroll
    for (int a = 0; a < 8; a++)
        #pragma unroll
        for (int t = 0; t < 4; t++) acc[a][t] = (f32x4){0.f, 0.f, 0.f, 0.f};

    bf16x8 bfr[2][4];
    float4 e0, e1, e2, e3;

    // prologue: e(c=0), bfr[0] <= tile pbase*24, pack X buf0, barrier
    {
        e0 = ((const float4*)embrow)[0];
        e1 = ((const float4*)embrow)[1];
        e2 = ((const float4*)embrow)[2];
        e3 = ((const float4*)embrow)[3];
        const unsigned short* bt = wbc + (size_t)(pbase * 24) * 8192 + vlaneB;
        #pragma unroll
        for (int t = 0; t < 4; t++)
            bfr[0][t] = *(const bf16x8*)(bt + t * 512);
        uint4 p0 = make_uint4(pk2(e0.x, e0.y), pk2(e0.z, e0.w),
                              pk2(e1.x, e1.y), pk2(e1.z, e1.w));
        uint4 p1 = make_uint4(pk2(e2.x, e2.y), pk2(e2.z, e2.w),
                              pk2(e3.x, e3.y), pk2(e3.z, e3.w));
        *(uint4*)&Xlds[xo0] = p0;
        *(uint4*)&Xlds[xo1] = p1;
        asm volatile("s_waitcnt lgkmcnt(0)" ::: "memory");
        __builtin_amdgcn_s_barrier();
    }

    int cbase = pbase * 24;    // uniform tile base, advances by 2 per c2
    for (int c2 = 0; c2 < 24; c2 += 2, cbase += 2) {
        #pragma unroll
        for (int s2 = 0; s2 < 2 * SZ; ++s2) {
            const int half = (s2 < SZ) ? 0 : 1;
            const int j    = s2 - half * SZ;
            const int par  = s2 & 1;
            // prefetch B(s2+1): compile-time tile offset from cbase
            {
                const int sP = s2 + 1;
                const int offP = (sP < SZ) ? sP * 24
                               : (sP < 2 * SZ ? (sP - SZ) * 24 + 1 : 2);
                const unsigned short* bt =
                    wbc + (size_t)(cbase + offP) * 8192 + vlaneB;
                #pragma unroll
                for (int t = 0; t < 4; t++)
                    bfr[par ^ 1][t] = *(const bf16x8*)(bt + t * 512);
            }
            if (s2 == 0 || s2 == SZ) {      // emb prefetch for next chunk
                int cE = half ? c2 + 2 : c2 + 1; if (cE > 23) cE = 0;
                const float* sp = embrow + cE * 32;
                e0 = ((const float4*)sp)[0];
                e1 = ((const float4*)sp)[1];
                e2 = ((const float4*)sp)[2];
                e3 = ((const float4*)sp)[3];
            }

            const unsigned short* Xb = Xlds + half * 4096;
            // group 1: rows 0..63 (sentence 0)
            {
                bf16x8 af[4];
                #pragma unroll
                for (int a = 0; a < 4; a++) {
                    int pp = 16 * a + l15 + j; if (pp > 63) pp = 63;
                    af[a] = *(const bf16x8*)(
                        &Xb[pp * 32 + ((q ^ ((pp >> 1) & 3)) * 8)]);
                }
                __builtin_amdgcn_s_setprio(1);
                #pragma unroll
                for (int a = 0; a < 4; a++)
                    #pragma unroll
                    for (int t = 0; t < 4; t++)
                        acc[a][t] = __builtin_amdgcn_mfma_f32_16x16x32_bf16(
                            af[a], bfr[par][t], acc[a][t], 0, 0, 0);
                __builtin_amdgcn_s_setprio(0);
            }
            // group 2: rows 64..127 (sentence 1)
            {
                bf16x8 af[4];
                #pragma unroll
                for (int a = 0; a < 4; a++) {
                    int pp = 16 * a + l15 + j; if (pp > 63) pp = 63;
                    int xr = 64 + pp;
                    af[a] = *(const bf16x8*)(
                        &Xb[xr * 32 + ((q ^ ((xr >> 1) & 3)) * 8)]);
                }
                __builtin_amdgcn_s_setprio(1);
                #pragma unroll
                for (int a = 0; a < 4; a++)
                    #pragma unroll
                    for (int t = 0; t < 4; t++)
                        acc[4 + a][t] = __builtin_amdgcn_mfma_f32_16x16x32_bf16(
                            af[a], bfr[par][t], acc[4 + a][t], 0, 0, 0);
                __builtin_amdgcn_s_setprio(0);
            }

            if (j == SZ - 1) {   // pack X(next chunk) into other buffer
                unsigned short* Xw = Xlds + (half ^ 1) * 4096;
                uint4 p0 = make_uint4(pk2(e0.x, e0.y), pk2(e0.z, e0.w),
                                      pk2(e1.x, e1.y), pk2(e1.z, e1.w));
                uint4 p1 = make_uint4(pk2(e2.x, e2.y), pk2(e2.z, e2.w),
                                      pk2(e3.x, e3.y), pk2(e3.z, e3.w));
                *(uint4*)&Xw[xo0] = p0;
                *(uint4*)&Xw[xo1] = p1;
                asm volatile("s_waitcnt lgkmcnt(0)" ::: "memory");
                __builtin_amdgcn_s_barrier();
            }
        }
    }

    // epilogue: relu(acc+bias), mask, maxpool, store bf16 rows t*8+b
    int pmax = 64 - SZ;
    #pragma unroll
    for (int t = 0; t < 4; t++) {
        int colb = nw * 64 + t * 16;
        float bias = cb[colb + l15];
        #pragma unroll
        for (int s = 0; s < 2; s++) {
            float m = 0.0f;
            #pragma unroll
            for (int a4 = 0; a4 < 4; a4++) {
                #pragma unroll
                for (int r = 0; r < 4; r++) {
                    int p = 16 * a4 + q * 4 + r;
                    float v = acc[s * 4 + a4][t][r] + bias;
                    v = v > 0.f ? v : 0.f;
                    if (p <= pmax) m = v > m ? v : m;
                }
            }
            m = fmaxf(m, __shfl_xor(m, 16));
            m = fmaxf(m, __shfl_xor(m, 32));
            if (lane < 16) {
                int n = n0 + s;
                int row = (n & 63) * 8 + (n >> 6);     // t*8 + b
                para_bf[(size_t)row * 768 + szi * 256 + colb + lane] =
                    (unsigned short)f2bf(m);
            }
        }
    }
}

__global__ __launch_bounds__(256, 2) void conv_pool_kernel(
    const int* __restrict__ ids,
    const float* __restrict__ emb,
    const unsigned short* __restrict__ wbc,
    const float* __restrict__ cb3, const float* __restrict__ cb4,
    const float* __restrict__ cb5,
    unsigned short* __restrict__ para_bf)
{
    __shared__ unsigned short Xlds[2][4096];   // 128 rows x 32 e, dbuf
    int bx   = blockIdx.x;
    int szi  = 2 - (bx >> 8);      // DESCENDING: conv5 blocks dispatch first
    int pair = bx & 255;
    if (szi == 0)
        conv_body<3>(ids, emb, wbc, cb3, para_bf, pair, 0, 0, &Xlds[0][0]);
    else if (szi == 1)
        conv_body<4>(ids, emb, wbc, cb4, para_bf, pair, 1, 3, &Xlds[0][0]);
    else
        conv_body<5>(ids, emb, wbc, cb5, para_bf, pair, 2, 7, &Xlds[0][0]);
}

// ---------------------------------------------------------------------------
// Kernel 3: LSTM input projection via MFMA. 4-deep K register pipeline.
// Output layout: gates2[dir][t][nn][8] (b fastest) -> lstm reads 1KB bursts.
// ---------------------------------------------------------------------------
template<int KC>
__global__ __launch_bounds__(256) void gemm_in_kernel(
    const unsigned short* __restrict__ xbf,   // [512][KC*32]
    const unsigned short* __restrict__ wihc,  // [2*KC] tiles
    const float* __restrict__ bihF, const float* __restrict__ bhhF,
    const float* __restrict__ bihB, const float* __restrict__ bhhB,
    float* __restrict__ gates2)               // [2][64][256][8]
{
    const int din = KC * 32;
    int bx   = blockIdx.x;
    int dir  = bx >> 4;
    int rowg = (bx >> 1) & 7;
    int colg = bx & 1;
    int tid  = threadIdx.x;
    int lane = tid & 63;
    int wid  = tid >> 6;
    int mw   = wid >> 1;
    int nw   = wid & 1;
    int l15  = lane & 15;
    int q    = lane >> 4;

    const float* bih = dir ? bihB : bihF;
    const float* bhh = dir ? bhhB : bhhF;
    const unsigned short* wt = wihc + (size_t)dir * KC * 8192;

    const unsigned short* arow[2];
    #pragma unroll
    for (int a = 0; a < 2; a++)
        arow[a] = xbf + (size_t)(rowg * 64 + mw * 32 + a * 16 + l15) * din + q * 8;
    const unsigned short* bbase = wt + (colg * 8 + nw * 4) * 512 + lane * 8;

    f32x4 acc[2][4];
    #pragma unroll
    for (int a = 0; a < 2; a++)
        #pragma unroll
        for (int t = 0; t < 4; t++) acc[a][t] = (f32x4){0.f, 0.f, 0.f, 0.f};

    bf16x8 afb[4][2], bfb[4][4];
    #pragma unroll
    for (int s = 0; s < 3; s++) {
        int k0 = (s < KC) ? s : KC - 1;
        #pragma unroll
        for (int a = 0; a < 2; a++)
            afb[s][a] = *(const bf16x8*)(arow[a] + k0 * 32);
        #pragma unroll
        for (int t = 0; t < 4; t++)
            bfb[s][t] = *(const bf16x8*)(bbase + (size_t)k0 * 8192 + t * 512);
    }

    #pragma unroll 4
    for (int kc = 0; kc < KC; ++kc) {
        const int p  = kc & 3;
        const int pn = (kc + 3) & 3;
        int kn = (kc + 3 < KC) ? kc + 3 : KC - 1;
        #pragma unroll
        for (int a = 0; a < 2; a++)
            afb[pn][a] = *(const bf16x8*)(arow[a] + kn * 32);
        #pragma unroll
        for (int t = 0; t < 4; t++)
            bfb[pn][t] = *(const bf16x8*)(bbase + (size_t)kn * 8192 + t * 512);
        #pragma unroll
        for (int a = 0; a < 2; a++)
            #pragma unroll
            for (int t = 0; t < 4; t++)
                acc[a][t] = __builtin_amdgcn_mfma_f32_16x16x32_bf16(
                    afb[p][a], bfb[p][t], acc[a][t], 0, 0, 0);
    }

    // epilogue: + (bih+bhh); store to [dir][t][nn][8] layout
    #pragma unroll
    for (int tt = 0; tt < 4; tt++) {
        int nn = colg * 128 + nw * 64 + tt * 16 + l15;
        float bb = bih[nn] + bhh[nn];
        #pragma unroll
        for (int a = 0; a < 2; a++) {
            int m = rowg * 64 + mw * 32 + q * 4 + a * 16;   // t*8+b
            int tcol = m >> 3, b0 = m & 7;
            f32x4 v = acc[a][tt];
            v[0] += bb; v[1] += bb; v[2] += bb; v[3] += bb;
            *(f32x4*)(gates2 + (((size_t)dir * 64 + tcol) * 256 + nn) * 8 + b0) = v;
        }
    }
}

// ---------------------------------------------------------------------------
// Kernel 4: LSTM recurrence via MFMA. 1 block/dir, 256 threads (4 waves).
// gates2[dir][t][nn][8]: wave's gate read = contiguous 1KB. 4-deep register
// prefetch pipeline. gv folded into MFMA C-in.
// ---------------------------------------------------------------------------
__global__ __launch_bounds__(256) void lstm_rec_kernel(
    const float* __restrict__ gates2,   // (2,64,256,8) + pad
    const float* __restrict__ WhhF, const float* __restrict__ WhhB, // (256,64)
    float* __restrict__ houtF,          // (64,8,128) or null
    unsigned short* __restrict__ houtB) // (64,8,128) bf16
{
    int dir = blockIdx.x;
    const float* Whh = dir ? WhhB : WhhF;
    const float* gin = gates2 + (size_t)dir * 64 * 256 * 8;

    __shared__ unsigned short h16[2][16 * 64];

    int tid  = threadIdx.x;
    int lane = tid & 63;
    int w    = tid >> 6;
    int l15  = lane & 15;
    int q    = lane >> 4;
    int hh   = 16 * w + l15;

    bf16x8 Bf[4][2];
    #pragma unroll
    for (int g = 0; g < 4; g++)
        #pragma unroll
        for (int kh = 0; kh < 2; kh++) {
            const float* wp = Whh + (size_t)(g * 64 + hh) * 64 + kh * 32 + q * 8;
            float4 f0 = *(const float4*)wp;
            float4 f1 = *(const float4*)(wp + 4);
            bf16x8 r;
            r[0] = (__bf16)f0.x; r[1] = (__bf16)f0.y;
            r[2] = (__bf16)f0.z; r[3] = (__bf16)f0.w;
            r[4] = (__bf16)f1.x; r[5] = (__bf16)f1.y;
            r[6] = (__bf16)f1.z; r[7] = (__bf16)f1.w;
            Bf[g][kh] = r;
        }

    // per-lane gate base: [nn=g*64+hh][4q]; t stride = 2048 floats
    const float* pgB[4];
    #pragma unroll
    for (int g = 0; g < 4; g++)
        pgB[g] = gin + (size_t)(g * 64 + hh) * 8 + 4 * q;

    for (int i = tid; i < 2 * 16 * 64; i += 256)
        ((unsigned short*)h16)[i] = 0;
    float cst[4] = {0.f, 0.f, 0.f, 0.f};
    __syncthreads();

    // 4-deep gv pipeline: slots 0..2 preloaded for steps 0..2
    f32x4 gvp[4][4];
    #pragma unroll
    for (int d = 0; d < 3; d++) {
        int td = dir ? 63 - d : d;
        #pragma unroll
        for (int g = 0; g < 4; g++)
            gvp[d][g] = *(const f32x4*)(pgB[g] + (size_t)td * 2048);
    }

    #pragma unroll 4
    for (int s = 0; s < 64; ++s) {
        const int slot = s & 3;
        int t = dir ? 63 - s : s;
        const unsigned short* hb = h16[s & 1];
        int slot0 = q ^ (l15 & 7);
        int slot1 = (4 + q) ^ (l15 & 7);
        bf16x8 a0 = *(const bf16x8*)&hb[l15 * 64 + slot0 * 8];
        bf16x8 a1 = *(const bf16x8*)&hb[l15 * 64 + slot1 * 8];

        f32x4 acc[4];
        #pragma unroll
        for (int g = 0; g < 4; g++) {
            acc[g] = __builtin_amdgcn_mfma_f32_16x16x32_bf16(a0, Bf[g][0], gvp[slot][g], 0, 0, 0);
            acc[g] = __builtin_amdgcn_mfma_f32_16x16x32_bf16(a1, Bf[g][1], acc[g], 0, 0, 0);
        }

        // prefetch step s+3 into slot (s+3)&3 (clamped dummy at tail)
        {
            int sn = (s + 3 < 64) ? s + 3 : 63;
            int tn = dir ? 63 - sn : sn;
            const int slotn = (s + 3) & 3;
            #pragma unroll
            for (int g = 0; g < 4; g++)
                gvp[slotn][g] = *(const f32x4*)(pgB[g] + (size_t)tn * 2048);
        }

        if (q < 2) {
            unsigned short* hw = h16[(s + 1) & 1];
            #pragma unroll
            for (int r = 0; r < 4; r++) {
                int b = 4 * q + r;
                float gi = acc[0][r];
                float gf = acc[1][r];
                float gg = acc[2][r];
                float go = acc[3][r];
                float cn = sigf(gf) * cst[r] + sigf(gi) * tanhff(gg);
                float hv = sigf(go) * tanhff(cn);
                cst[r] = cn;
                int slotw = (hh >> 3) ^ (b & 7);
                hw[b * 64 + slotw * 8 + (hh & 7)] = (unsigned short)f2bf(hv);
                size_t oi = ((size_t)t * 8 + b) * 128 + dir * 64 + hh;
                if (houtF) houtF[oi] = hv;
                houtB[oi] = (unsigned short)f2bf(hv);
            }
        }
        __syncthreads();
    }
}

// ---------------------------------------------------------------------------
// Kernel 5: feats + CRF scan + gold, single block, LDS-staged
// ---------------------------------------------------------------------------
__global__ __launch_bounds__(512) void crf_kernel(
    const float* __restrict__ h1,       // (64,8,128)
    const float* __restrict__ lin_w,    // (5,128)
    const float* __restrict__ lin_b,    // (5)
    const float* __restrict__ mask,     // (64,8)
    const int* __restrict__ tags,       // (64,8)
    const float* __restrict__ trans,    // (5,5)
    float* __restrict__ out) {
    __shared__ float feats[64][8][5];
    __shared__ float wl[5][128];
    __shared__ float msk[512];
    __shared__ int   tgs[512];
    __shared__ float fwd_s[8], gold_s[8];
    __shared__ float tr[25], trE[5], lb[5];
    int tid = threadIdx.x;
    if (tid < 25) tr[tid] = trans[tid];
    if (tid < 5) { trE[tid] = trans[20 + tid]; lb[tid] = lin_b[tid]; }
    msk[tid] = mask[tid];
    tgs[tid] = tags[tid];
    if (tid < 128) {
        #pragma unroll
        for (int i = 0; i < 5; i++) wl[i][tid] = lin_w[i * 128 + tid];
    }
    __syncthreads();

    {
        const float4* h4 = (const float4*)(h1 + (size_t)tid * 128);
        float a0 = 0.f, a1 = 0.f, a2 = 0.f, a3 = 0.f, a4 = 0.f;
        for (int e4 = 0; e4 < 32; e4++) {
            float4 hv = h4[e4];
            int e = e4 * 4;
            a0 += hv.x * wl[0][e] + hv.y * wl[0][e+1] + hv.z * wl[0][e+2] + hv.w * wl[0][e+3];
            a1 += hv.x * wl[1][e] + hv.y * wl[1][e+1] + hv.z * wl[1][e+2] + hv.w * wl[1][e+3];
            a2 += hv.x * wl[2][e] + hv.y * wl[2][e+1] + hv.z * wl[2][e+2] + hv.w * wl[2][e+3];
            a3 += hv.x * wl[3][e] + hv.y * wl[3][e+1] + hv.z * wl[3][e+2] + hv.w * wl[3][e+3];
            a4 += hv.x * wl[4][e] + hv.y * wl[4][e+1] + hv.z * wl[4][e+2] + hv.w * wl[4][e+3];
        }
        float m = msk[tid];
        int t = tid >> 3, b = tid & 7;
        feats[t][b][0] = (m * a0 + lb[0]) * m;
        feats[t][b][1] = (m * a1 + lb[1]) * m;
        feats[t][b][2] = (m * a2 + lb[2]) * m;
        feats[t][b][3] = (m * a3 + lb[3]) * m;
        feats[t][b][4] = (m * a4 + lb[4]) * m;
    }
    __syncthreads();

    if (tid < 40) {    // wave 0, lane = b*5+i
        int b = tid / 5, i = tid % 5;
        float alpha = (i == 0) ? 0.f : NEG_VAL;
        float trow[5];
        #pragma unroll
        for (int j2 = 0; j2 < 5; j2++) trow[j2] = tr[i * 5 + j2];
        for (int t = 0; t < 64; t++) {
            float s0, s1, s2, s3, s4;
            s0 = __shfl(alpha, b * 5 + 0, 64) + trow[0];
            s1 = __shfl(alpha, b * 5 + 1, 64) + trow[1];
            s2 = __shfl(alpha, b * 5 + 2, 64) + trow[2];
            s3 = __shfl(alpha, b * 5 + 3, 64) + trow[3];
            s4 = __shfl(alpha, b * 5 + 4, 64) + trow[4];
            float mx = fmaxf(fmaxf(fmaxf(s0, s1), fmaxf(s2, s3)), s4);
            float sum = expf(s0 - mx) + expf(s1 - mx) + expf(s2 - mx) +
                        expf(s3 - mx) + expf(s4 - mx);
            float lse = mx + logf(sum) + feats[t][b][i];
            float mt = msk[t * 8 + b];
            alpha = mt * lse + (1.f - mt) * alpha;
        }
        float v = alpha + trE[i];
        float m0 = __shfl(v, b * 5 + 0, 64);
        float m1 = __shfl(v, b * 5 + 1, 64);
        float m2 = __shfl(v, b * 5 + 2, 64);
        float m3 = __shfl(v, b * 5 + 3, 64);
        float m4 = __shfl(v, b * 5 + 4, 64);
        float mx = fmaxf(fmaxf(fmaxf(m0, m1), fmaxf(m2, m3)), m4);
        float sum = expf(m0 - mx) + expf(m1 - mx) + expf(m2 - mx) +
                    expf(m3 - mx) + expf(m4 - mx);
        if (i == 0) fwd_s[b] = mx + logf(sum);
    }
    if (tid >= 64 && tid < 72) {
        int b = tid - 64;
        float g = 0.f, lenf = 0.f;
        int prev = 0;   // SOS
        for (int t = 0; t < 64; t++) {
            int tg = tgs[t * 8 + b];
            float mt = msk[t * 8 + b];
            g += (feats[t][b][tg] + tr[tg * 5 + prev]) * mt;
            lenf += mt;
            prev = tg;
        }
        int len = (int)lenf;
        int last = (len == 0) ? 0 : tgs[(len - 1) * 8 + b];
        g += trE[last];
        gold_s[b] = g;
    }
    __syncthreads();
    if (tid == 0) {
        float s = 0.f;
        for (int b = 0; b < 8; b++) s += fwd_s[b] - gold_s[b];
        out[0] = s;
    }
}

// ---------------------------------------------------------------------------
extern "C" void kernel_launch(void* const* d_in, const int* in_sizes, int n_in,
                              void* d_out, int out_size, void* d_ws, size_t ws_size,
                              hipStream_t stream) {
    const int*   ids   = (const int*)d_in[0];
    const int*   tags  = (const int*)d_in[1];
    const float* mask  = (const float*)d_in[2];
    const float* emb   = (const float*)d_in[4];
    const float* cw3   = (const float*)d_in[5];
    const float* cb3   = (const float*)d_in[6];
    const float* cw4   = (const float*)d_in[7];
    const float* cb4   = (const float*)d_in[8];
    const float* cw5   = (const float*)d_in[9];
    const float* cb5   = (const float*)d_in[10];
    const float* Wih0f = (const float*)d_in[11];
    const float* Whh0f = (const float*)d_in[12];
    const float* bih0f = (const float*)d_in[13];
    const float* bhh0f = (const float*)d_in[14];
    const float* Wih0b = (const float*)d_in[15];
    const float* Whh0b = (const float*)d_in[16];
    const float* bih0b = (const float*)d_in[17];
    const float* bhh0b = (const float*)d_in[18];
    const float* Wih1f = (const float*)d_in[19];
    const float* Whh1f = (const float*)d_in[20];
    const float* bih1f = (const float*)d_in[21];
    const float* bhh1f = (const float*)d_in[22];
    const float* Wih1b = (const float*)d_in[23];
    const float* Whh1b = (const float*)d_in[24];
    const float* bih1b = (const float*)d_in[25];
    const float* bhh1b = (const float*)d_in[26];
    const float* lin_w = (const float*)d_in[27];
    const float* lin_b = (const float*)d_in[28];
    const float* trans = (const float*)d_in[29];

    char* ws = (char*)d_ws;
    unsigned short* wbc     = (unsigned short*)ws;
    unsigned short* wih0c   = (unsigned short*)(ws + 4718592);
    unsigned short* wih1c   = (unsigned short*)(ws + 5505024);
    unsigned short* para_bf = (unsigned short*)(ws + 5636096);
    float*          gates   = (float*)(ws + 6422528);   // 1MB + pad tail
    unsigned short* h0_bf   = (unsigned short*)(ws + 5636096);
    float*          h1f     = (float*)(ws + 4718592);

    hipLaunchKernelGGL(cast_all_kernel, dim3(1376), dim3(256), 0, stream,
                       cw3, cw4, cw5, Wih0f, Wih0b, Wih1f, Wih1b,
                       wbc, wih0c, wih1c);
    hipLaunchKernelGGL(conv_pool_kernel, dim3(768), dim3(256), 0, stream,
                       ids, emb, wbc, cb3, cb4, cb5, para_bf);
    hipLaunchKernelGGL((gemm_in_kernel<24>), dim3(32), dim3(256), 0, stream,
                       para_bf, wih0c, bih0f, bhh0f, bih0b, bhh0b, gates);
    hipLaunchKernelGGL(lstm_rec_kernel, dim3(2), dim3(256), 0, stream,
                       gates, Whh0f, Whh0b, (float*)nullptr, h0_bf);
    hipLaunchKernelGGL((gemm_in_kernel<4>), dim3(32), dim3(256), 0, stream,
                       h0_bf, wih1c, bih1f, bhh1f, bih1b, bhh1b, gates);
    hipLaunchKernelGGL(lstm_rec_kernel, dim3(2), dim3(256), 0, stream,
                       gates, Whh1f, Whh1b, h1f, h0_bf);
    hipLaunchKernelGGL(crf_kernel, dim3(1), dim3(512), 0, stream,
                       h1f, lin_w, lin_b, mask, tags, trans, (float*)d_out);
}